// Round 5
// baseline (1005.235 us; speedup 1.0000x reference)
//
#include <hip/hip_runtime.h>
#include <hip/hip_bf16.h>
#include <math.h>

// ---------------------------------------------------------------------------
// SwinTransformerBlock1D.  Inputs fp32, output fp32, internal bf16 MFMA.
// B=4 L=8192 DIM=512 HEADS=8 WIN=256 HEAD_DIM=64 HID=2048.
// R5: gemm128 LDS staging switched to MFMA-fragment order (lane-linear
// ds_read_b128, zero bank conflicts -- R4 had 16-way conflicts = 5.7x LDS
// slowdown, 2.5e7 SQ_LDS_BANK_CONFLICT) + XCD-aware block swizzle (A-band
// and B stay L2-resident per XCD; R4 FETCH showed 8x A re-fetch).
// MFMA fragment layouts (m89/m91-verified): A[m=lane&15][k=quad*8+j],
// B[n=lane&15][k=quad*8+j], D[row=quad*4+r][col=lane&15].
// ---------------------------------------------------------------------------

typedef __attribute__((ext_vector_type(8))) __bf16 bf16x8;
typedef __attribute__((ext_vector_type(4))) __bf16 bf16x4;
typedef __attribute__((ext_vector_type(4))) float  f32x4;

#define NTOK  32768
#define DIMC  512
#define HEADS 8
#define WIN   256
#define HD    64
#define HIDC  2048
#define LDP   40   // padded LDS k-stride for 64-tile attention kernels

// async global->LDS, 16B per lane; LDS dest = wave-uniform base + lane*16B
__device__ __forceinline__ void gld16(const __bf16* g, __bf16* l)
{
    __builtin_amdgcn_global_load_lds(
        (const __attribute__((address_space(1))) void*)g,
        (__attribute__((address_space(3))) void*)l, 16, 0, 0);
}

// ---------------- 128x128 GEMM, fragment-order LDS, XCD swizzle ------------
// A (MxK row-major), Bt (NxK row-major).
// LDS: 16 A-tiles + 16 B-tiles of 512 elems (16 rows x 32 k in lane order).
// Tile T = msub*2 + ks  (msub 0..7 = 16-row group, ks 0..1 = 32-k slice).
// MODE 0: C = A@W + bias          (qkv)
// MODE 1: C = A@W + bias + res    (proj+shortcut, fc2+x2)
// MODE 2: C = gelu(A@W + bias)    (fc1, exact gelu)
// OUTF 0: C bf16 (internal)  OUTF 1: C fp32 (final output)
template<int MODE, int OUTF>
__global__ __launch_bounds__(256, 4) void gemm128(
    const __bf16* __restrict__ A, int lda,
    const __bf16* __restrict__ Bt, int ldb,
    const float* __restrict__ bias,
    const void* __restrict__ res, int res_f32,
    void* __restrict__ C, int ldc, int K,
    int nM, int nN)
{
    __shared__ __bf16 As[16 * 512];
    __shared__ __bf16 Bs[16 * 512];
    const int tid  = threadIdx.x;
    const int wave = tid >> 6, lane = tid & 63;
    const int quad = lane >> 4, l16 = lane & 15;
    const int wr = wave >> 1, wn = wave & 1;       // 2x2 wave grid

    // XCD swizzle: id%8 = XCD (round-robin dispatch assumption); each XCD
    // owns nM/8 consecutive m-tiles and sweeps all n-tiles for each.
    const int id  = blockIdx.x;
    const int xcd = id & 7;
    const int lid = id >> 3;
    const int mq  = lid / nN;
    const int mt  = xcd * (nM >> 3) + mq;
    const int nt  = lid - mq * nN;
    const int m0 = mt * 128, n0 = nt * 128;

    // staging: wave stages tiles T = wave*4+j for both A and B.
    // lane i -> row (T>>1)*16 + (i&15), k-off (T&1)*32 + (i>>4)*8.
    const __bf16* ag[4];
    const __bf16* bg[4];
    __bf16* al[4];
    __bf16* bl[4];
    #pragma unroll
    for (int j = 0; j < 4; j++) {
        const int T = wave * 4 + j;
        const int row = (T >> 1) * 16 + l16;
        const int koff = (T & 1) * 32 + quad * 8;
        ag[j] = A  + (size_t)(m0 + row) * lda + koff;
        bg[j] = Bt + (size_t)(n0 + row) * ldb + koff;
        al[j] = As + T * 512;
        bl[j] = Bs + T * 512;
    }

    f32x4 acc[4][4] = {};
    for (int k0 = 0; k0 < K; k0 += 64) {
        __syncthreads();                 // prev iter's fragment reads done
        #pragma unroll
        for (int j = 0; j < 4; j++) {
            gld16(ag[j] + k0, al[j]);
            gld16(bg[j] + k0, bl[j]);
        }
        __syncthreads();                 // vmcnt(0) drain + barrier
        #pragma unroll
        for (int ks = 0; ks < 2; ks++) {
            bf16x8 af[4], bfr[4];
            #pragma unroll
            for (int i = 0; i < 4; i++) {
                af[i]  = *(const bf16x8*)(As + ((wr * 4 + i) * 2 + ks) * 512 + lane * 8);
                bfr[i] = *(const bf16x8*)(Bs + ((wn * 4 + i) * 2 + ks) * 512 + lane * 8);
            }
            #pragma unroll
            for (int mi = 0; mi < 4; mi++)
                #pragma unroll
                for (int ni = 0; ni < 4; ni++)
                    acc[mi][ni] = __builtin_amdgcn_mfma_f32_16x16x32_bf16(
                        af[mi], bfr[ni], acc[mi][ni], 0, 0, 0);
        }
    }
    // epilogue
    #pragma unroll
    for (int ni = 0; ni < 4; ni++) {
        const int col = n0 + wn * 64 + ni * 16 + l16;
        const float bv = bias[col];
        #pragma unroll
        for (int mi = 0; mi < 4; mi++) {
            #pragma unroll
            for (int r = 0; r < 4; r++) {
                const int row = m0 + wr * 64 + mi * 16 + quad * 4 + r;
                const size_t off = (size_t)row * ldc + col;
                float v = acc[mi][ni][r] + bv;
                if (MODE == 2) v = 0.5f * v * (1.0f + erff(v * 0.70710678118654752f));
                if (MODE == 1)
                    v += res_f32 ? ((const float*)res)[off]
                                 : (float)((const __bf16*)res)[off];
                if (OUTF) ((float*)C)[off] = v;
                else      ((__bf16*)C)[off] = (__bf16)v;
            }
        }
    }
}

// ---------------- 64x64 MFMA tile helper (attention kernels) ---------------
__device__ __forceinline__ void mfma_tile64(
    const __bf16* __restrict__ A, int lda, int m0,
    const __bf16* __restrict__ Bt, int ldb, int n0,
    int K, f32x4* acc, __bf16* As, __bf16* Bs)
{
    const int tid  = threadIdx.x;
    const int wave = tid >> 6;
    const int lane = tid & 63;
    const int quad = lane >> 4;
    const int l16  = lane & 15;
    const int lrow = tid >> 2;          // 0..63
    const int lcol = (tid & 3) << 3;    // 0,8,16,24
    const __bf16* ap = A  + (size_t)(m0 + lrow) * lda + lcol;
    const __bf16* bp = Bt + (size_t)(n0 + lrow) * ldb + lcol;
    for (int k0 = 0; k0 < K; k0 += 32) {
        bf16x8 av = *(const bf16x8*)(ap + k0);
        bf16x8 bv = *(const bf16x8*)(bp + k0);
        __syncthreads();
        *(bf16x8*)(As + lrow * LDP + lcol) = av;
        *(bf16x8*)(Bs + lrow * LDP + lcol) = bv;
        __syncthreads();
        bf16x8 af = *(const bf16x8*)(As + (wave * 16 + l16) * LDP + (quad << 3));
        #pragma unroll
        for (int nb = 0; nb < 4; nb++) {
            bf16x8 bf = *(const bf16x8*)(Bs + (nb * 16 + l16) * LDP + (quad << 3));
            acc[nb] = __builtin_amdgcn_mfma_f32_16x16x32_bf16(af, bf, acc[nb], 0, 0, 0);
        }
    }
}

// ---------------- QK^T: S = (Q@K^T)*scale + rpb_bias -----------------------
__global__ __launch_bounds__(256) void qk_gemm(
    const __bf16* __restrict__ qkvb, const float* __restrict__ rpb,
    __bf16* __restrict__ Sc, int bh_base)
{
    __shared__ __align__(16) __bf16 As[64 * LDP];
    __shared__ __align__(16) __bf16 Bs[64 * LDP];
    const int bhl = blockIdx.z;
    const int bh = bh_base + bhl;
    const int bw = bh >> 3, head = bh & 7;
    const int m0 = blockIdx.y * 64, n0 = blockIdx.x * 64;
    const __bf16* Aq = qkvb + (size_t)bw * WIN * 1536 + head * HD;       // q rows
    const __bf16* Bk = Aq + 512;                                         // k rows
    f32x4 acc[4] = {};
    mfma_tile64(Aq, 1536, m0, Bk, 1536, n0, HD, acc, As, Bs);
    const int lane = threadIdx.x & 63, wave = threadIdx.x >> 6;
    const int quad = lane >> 4, l16 = lane & 15;
    __bf16* Sb = Sc + (size_t)bhl * (WIN * WIN);
    #pragma unroll
    for (int nb = 0; nb < 4; nb++) {
        const int j = n0 + nb * 16 + l16;
        #pragma unroll
        for (int r = 0; r < 4; r++) {
            const int i = m0 + wave * 16 + quad * 4 + r;
            float s = acc[nb][r] * 0.125f + rpb[(size_t)(i - j + WIN - 1) * HEADS + head];
            Sb[(size_t)i * WIN + j] = (__bf16)s;
        }
    }
}

// ---------------- row softmax over S chunk (in place) ----------------------
__global__ __launch_bounds__(256) void softmax_rows(__bf16* __restrict__ Sc)
{
    const int rid  = blockIdx.x * 4 + (threadIdx.x >> 6);
    const int lane = threadIdx.x & 63;
    __bf16* row = Sc + (size_t)rid * WIN + lane * 4;
    bf16x4 xv = *(const bf16x4*)row;
    float v[4];
    float m = -1e30f;
    #pragma unroll
    for (int t = 0; t < 4; t++) { v[t] = (float)xv[t]; m = fmaxf(m, v[t]); }
    #pragma unroll
    for (int off = 32; off; off >>= 1) m = fmaxf(m, __shfl_xor(m, off));
    float s = 0.f;
    #pragma unroll
    for (int t = 0; t < 4; t++) { v[t] = __expf(v[t] - m); s += v[t]; }
    #pragma unroll
    for (int off = 32; off; off >>= 1) s += __shfl_xor(s, off);
    const float inv = 1.0f / s;
    bf16x4 ov;
    #pragma unroll
    for (int t = 0; t < 4; t++) ov[t] = (__bf16)(v[t] * inv);
    *(bf16x4*)row = ov;
}

// ---------------- V^T per (window,head): Vt[d][j] = V[j][d] ----------------
__global__ __launch_bounds__(256) void vtrans(
    const __bf16* __restrict__ qkvb, __bf16* __restrict__ Vt, int bh_base)
{
    __shared__ __align__(16) __bf16 s[WIN * 72];
    const int bh = bh_base + blockIdx.x;
    const int bw = bh >> 3, head = bh & 7;
    const int tid = threadIdx.x;
    const __bf16* V = qkvb + (size_t)bw * WIN * 1536 + 1024 + head * HD;
    #pragma unroll
    for (int it = 0; it < 8; it++) {
        int idx = it * 256 + tid;
        int j = idx >> 3;
        int d0 = (idx & 7) * 8;
        *(bf16x8*)(s + j * 72 + d0) = *(const bf16x8*)(V + (size_t)j * 1536 + d0);
    }
    __syncthreads();
    __bf16* out = Vt + (size_t)blockIdx.x * (HD * WIN);
    #pragma unroll
    for (int it = 0; it < 8; it++) {
        int idx = it * 256 + tid;
        int d  = idx >> 5;
        int j0 = (idx & 31) * 8;
        bf16x8 v;
        #pragma unroll
        for (int j = 0; j < 8; j++) v[j] = s[(j0 + j) * 72 + d];
        *(bf16x8*)(out + (size_t)d * WIN + j0) = v;
    }
}

// ---------------- P@V -> attn_out ------------------------------------------
__global__ __launch_bounds__(256) void pv_gemm(
    const __bf16* __restrict__ Sc, const __bf16* __restrict__ Vt,
    __bf16* __restrict__ attnO, int bh_base)
{
    __shared__ __align__(16) __bf16 As[64 * LDP];
    __shared__ __align__(16) __bf16 Bs[64 * LDP];
    const int bhl = blockIdx.y;
    const int bh = bh_base + bhl;
    const int bw = bh >> 3, head = bh & 7;
    const int m0 = blockIdx.x * 64;
    const __bf16* P   = Sc + (size_t)bhl * (WIN * WIN);
    const __bf16* Vtb = Vt + (size_t)bhl * (HD * WIN);
    f32x4 acc[4] = {};
    mfma_tile64(P, WIN, m0, Vtb, WIN, 0, WIN, acc, As, Bs);
    const int lane = threadIdx.x & 63, wave = threadIdx.x >> 6;
    const int quad = lane >> 4, l16 = lane & 15;
    #pragma unroll
    for (int nb = 0; nb < 4; nb++) {
        const int d = nb * 16 + l16;
        #pragma unroll
        for (int r = 0; r < 4; r++) {
            const int i = m0 + wave * 16 + quad * 4 + r;
            attnO[(size_t)(bw * WIN + i) * DIMC + head * HD + d] = (__bf16)acc[nb][r];
        }
    }
}

// ---------------- LayerNorm: one wave per token ----------------------------
__global__ __launch_bounds__(256) void ln_kernel(
    const void* X, int xf,
    const float* __restrict__ g, const float* __restrict__ b,
    __bf16* O)
{
    const int tok  = blockIdx.x * 4 + (threadIdx.x >> 6);
    const int lane = threadIdx.x & 63;
    const size_t base = (size_t)tok * DIMC + lane * 8;
    float v[8];
    if (xf) {
        const float* xp = (const float*)X + base;
        f32x4 a = *(const f32x4*)xp;
        f32x4 c = *(const f32x4*)(xp + 4);
        #pragma unroll
        for (int j = 0; j < 4; j++) { v[j] = a[j]; v[4 + j] = c[j]; }
    } else {
        bf16x8 xv = *(const bf16x8*)((const __bf16*)X + base);
        #pragma unroll
        for (int j = 0; j < 8; j++) v[j] = (float)xv[j];
    }
    float s = 0.f, s2 = 0.f;
    #pragma unroll
    for (int j = 0; j < 8; j++) { s += v[j]; s2 += v[j] * v[j]; }
    #pragma unroll
    for (int off = 32; off; off >>= 1) { s += __shfl_xor(s, off); s2 += __shfl_xor(s2, off); }
    const float mean = s * (1.0f / DIMC);
    const float var  = s2 * (1.0f / DIMC) - mean * mean;
    const float rstd = rsqrtf(var + 1e-5f);
    f32x4 ga = *(const f32x4*)(g + lane * 8);
    f32x4 gc = *(const f32x4*)(g + lane * 8 + 4);
    f32x4 ba = *(const f32x4*)(b + lane * 8);
    f32x4 bc = *(const f32x4*)(b + lane * 8 + 4);
    bf16x8 ov;
    #pragma unroll
    for (int j = 0; j < 4; j++) {
        ov[j]     = (__bf16)((v[j]     - mean) * rstd * ga[j] + ba[j]);
        ov[4 + j] = (__bf16)((v[4 + j] - mean) * rstd * gc[j] + bc[j]);
    }
    *(bf16x8*)(O + base) = ov;
}

// ---------------- weight transpose+cast: fp32 KxN -> bf16 NxK --------------
__global__ __launch_bounds__(256) void wtrans(
    const float* __restrict__ W, __bf16* __restrict__ Wt, int K, int N)
{
    __shared__ __align__(16) __bf16 s[64 * 72];
    const int kb = blockIdx.y * 64, nb = blockIdx.x * 64;
    const int tid = threadIdx.x;
    #pragma unroll
    for (int it = 0; it < 2; it++) {
        int idx = it * 256 + tid;
        int lk = idx >> 3;
        int ln = (idx & 7) * 8;
        const float* wp = W + (size_t)(kb + lk) * N + nb + ln;
        f32x4 a = *(const f32x4*)wp;
        f32x4 c = *(const f32x4*)(wp + 4);
        bf16x8 v;
        #pragma unroll
        for (int j = 0; j < 4; j++) { v[j] = (__bf16)a[j]; v[4 + j] = (__bf16)c[j]; }
        *(bf16x8*)(s + lk * 72 + ln) = v;
    }
    __syncthreads();
    #pragma unroll
    for (int it = 0; it < 2; it++) {
        int idx = it * 256 + tid;
        int ln  = idx >> 3;
        int lkv = (idx & 7) * 8;
        bf16x8 v;
        #pragma unroll
        for (int j = 0; j < 8; j++) v[j] = s[(lkv + j) * 72 + ln];
        *(bf16x8*)(Wt + (size_t)(nb + ln) * K + kb + lkv) = v;
    }
}

// ---------------------------------------------------------------------------
extern "C" void kernel_launch(void* const* d_in, const int* in_sizes, int n_in,
                              void* d_out, int out_size, void* d_ws, size_t ws_size,
                              hipStream_t stream)
{
    const float* x      = (const float*)d_in[0];
    const float* n1g    = (const float*)d_in[1];
    const float* n1b    = (const float*)d_in[2];
    const float* qkv_w  = (const float*)d_in[3];
    const float* qkv_b  = (const float*)d_in[4];
    const float* rpb    = (const float*)d_in[5];
    const float* proj_w = (const float*)d_in[6];
    const float* proj_b = (const float*)d_in[7];
    const float* n2g    = (const float*)d_in[8];
    const float* n2b    = (const float*)d_in[9];
    const float* fc1_w  = (const float*)d_in[10];
    const float* fc1_b  = (const float*)d_in[11];
    const float* fc2_w  = (const float*)d_in[12];
    const float* fc2_b  = (const float*)d_in[13];
    float* out = (float*)d_out;

    // workspace layout (bytes), 216 MB peak; slots reused sequentially
    char* ws = (char*)d_ws;
    __bf16* qkvb  = (__bf16*)(ws + 0);
    __bf16* hid   = (__bf16*)(ws + 0);
    __bf16* h     = (__bf16*)(ws + 134217728);   // also Sc slot, also y/x2
    __bf16* Sc    = h;
    __bf16* y     = h;
    __bf16* attnO = (__bf16*)(ws + 167772160);
    __bf16* Vt    = (__bf16*)(ws + 201326592);
    __bf16* wq_t  = (__bf16*)(ws + 209715200);   // 1536x512
    __bf16* wp_t  = (__bf16*)(ws + 211288064);   // 512x512
    __bf16* w1_t  = (__bf16*)(ws + 211812352);   // 2048x512
    __bf16* w2_t  = (__bf16*)(ws + 213909504);   // 512x2048

    // 1) weight transposes (tiny)
    wtrans<<<dim3(1536 / 64, 512 / 64),  256, 0, stream>>>(qkv_w, wq_t, 512, 1536);
    wtrans<<<dim3(512 / 64,  512 / 64),  256, 0, stream>>>(proj_w, wp_t, 512, 512);
    wtrans<<<dim3(2048 / 64, 512 / 64),  256, 0, stream>>>(fc1_w, w1_t, 512, 2048);
    wtrans<<<dim3(512 / 64,  2048 / 64), 256, 0, stream>>>(fc2_w, w2_t, 2048, 512);

    // 2) LN1: h = LN(x)
    ln_kernel<<<NTOK / 4, 256, 0, stream>>>(x, 1, n1g, n1b, h);

    // 3) qkv = h @ qkv_w + qkv_b   (M=32768, N=1536, K=512); nM=256 nN=12
    gemm128<0, 0><<<3072, 256, 0, stream>>>(
        h, DIMC, wq_t, DIMC, qkv_b, nullptr, 0, qkvb, 1536, DIMC, 256, 12);

    // 4) attention in 4 chunks of 256 (window,head) pairs
    for (int c = 0; c < 4; c++) {
        const int bh0 = c * 256;
        vtrans<<<256, 256, 0, stream>>>(qkvb, Vt, bh0);
        qk_gemm<<<dim3(4, 4, 256), 256, 0, stream>>>(qkvb, rpb, Sc, bh0);
        softmax_rows<<<256 * WIN / 4, 256, 0, stream>>>(Sc);
        pv_gemm<<<dim3(4, 256), 256, 0, stream>>>(Sc, Vt, attnO, bh0);
    }

    // 5) y = x + attnO @ proj_w + proj_b   (N=512, K=512); nM=256 nN=4
    gemm128<1, 0><<<1024, 256, 0, stream>>>(
        attnO, DIMC, wp_t, DIMC, proj_b, x, 1, y, DIMC, DIMC, 256, 4);

    // 6) LN2 in place: x2 = LN(y)
    ln_kernel<<<NTOK / 4, 256, 0, stream>>>(y, 0, n2g, n2b, y);

    // 7) hid = gelu(x2 @ fc1_w + fc1_b)   (N=2048, K=512); nM=256 nN=16
    gemm128<2, 0><<<4096, 256, 0, stream>>>(
        y, DIMC, w1_t, DIMC, fc1_b, nullptr, 0, hid, HIDC, DIMC, 256, 16);

    // 8) out(fp32) = x2 + hid @ fc2_w + fc2_b  (N=512, K=2048); nM=256 nN=4
    gemm128<1, 1><<<1024, 256, 0, stream>>>(
        hid, HIDC, w2_t, HIDC, fc2_b, y, 0, out, DIMC, HIDC, 256, 4);
}

// Round 6
// 858.556 us; speedup vs baseline: 1.1708x; 1.1708x over previous
//
#include <hip/hip_runtime.h>
#include <hip/hip_bf16.h>
#include <math.h>

// ---------------------------------------------------------------------------
// SwinTransformerBlock1D.  Inputs fp32, output fp32, internal bf16 MFMA.
// B=4 L=8192 DIM=512 HEADS=8 WIN=256 HEAD_DIM=64 HID=2048.
// R6: (a) gemm128 = R5 conflict-free fragment-order staging + XCD swizzle,
//     but WITHOUT the (256,4) launch bound that capped VGPRs at 64 and
//     caused scratch spills (R5: VALUBusy 16->8%, dur +8%).
//     (b) qk_gemm + softmax fused into qk_softmax (64x256 stripe per block,
//     softmax in registers via shfl_xor over 16-lane groups, rpb bias from
//     LDS). Removes 4x16384-block softmax kernel + 64MB/chunk Sc round-trip.
// MFMA fragment layouts (m89/m91-verified): A[m=lane&15][k=quad*8+j],
// B[n=lane&15][k=quad*8+j], D[row=quad*4+r][col=lane&15].
// ---------------------------------------------------------------------------

typedef __attribute__((ext_vector_type(8))) __bf16 bf16x8;
typedef __attribute__((ext_vector_type(4))) __bf16 bf16x4;
typedef __attribute__((ext_vector_type(4))) float  f32x4;

#define NTOK  32768
#define DIMC  512
#define HEADS 8
#define WIN   256
#define HD    64
#define HIDC  2048
#define LDP   40   // padded LDS k-stride for 64-tile attention kernels

// async global->LDS, 16B per lane; LDS dest = wave-uniform base + lane*16B
__device__ __forceinline__ void gld16(const __bf16* g, __bf16* l)
{
    __builtin_amdgcn_global_load_lds(
        (const __attribute__((address_space(1))) void*)g,
        (__attribute__((address_space(3))) void*)l, 16, 0, 0);
}

// ---------------- 128x128 GEMM, fragment-order LDS, XCD swizzle ------------
// A (MxK row-major), Bt (NxK row-major).
// LDS: 16 A-tiles + 16 B-tiles of 512 elems (16 rows x 32 k, lane order).
// Tile T = msub*2 + ks  (msub 0..7 = 16-row group, ks 0..1 = 32-k slice).
// MODE 0: C = A@W + bias; 1: +res; 2: gelu.  OUTF 1: fp32 out.
template<int MODE, int OUTF>
__global__ __launch_bounds__(256) void gemm128(
    const __bf16* __restrict__ A, int lda,
    const __bf16* __restrict__ Bt, int ldb,
    const float* __restrict__ bias,
    const void* __restrict__ res, int res_f32,
    void* __restrict__ C, int ldc, int K,
    int nM, int nN)
{
    __shared__ __bf16 As[16 * 512];
    __shared__ __bf16 Bs[16 * 512];
    const int tid  = threadIdx.x;
    const int wave = tid >> 6, lane = tid & 63;
    const int quad = lane >> 4, l16 = lane & 15;
    const int wr = wave >> 1, wn = wave & 1;       // 2x2 wave grid

    // XCD swizzle: id%8 = XCD; each XCD owns nM/8 consecutive m-tiles.
    const int id  = blockIdx.x;
    const int xcd = id & 7;
    const int lid = id >> 3;
    const int mq  = lid / nN;
    const int mt  = xcd * (nM >> 3) + mq;
    const int nt  = lid - mq * nN;
    const int m0 = mt * 128, n0 = nt * 128;

    // staging: wave stages tiles T = wave*4+j (A and B); lane i ->
    // row (T>>1)*16 + (i&15), k (T&1)*32 + (i>>4)*8, LDS elem T*512 + i*8.
    const __bf16* ag[4];
    const __bf16* bg[4];
    #pragma unroll
    for (int j = 0; j < 4; j++) {
        const int T = wave * 4 + j;
        const int row = (T >> 1) * 16 + l16;
        const int koff = (T & 1) * 32 + quad * 8;
        ag[j] = A  + (size_t)(m0 + row) * lda + koff;
        bg[j] = Bt + (size_t)(n0 + row) * ldb + koff;
    }
    __bf16* asw = As + wave * 2048;
    __bf16* bsw = Bs + wave * 2048;

    f32x4 acc[4][4] = {};
    for (int k0 = 0; k0 < K; k0 += 64) {
        __syncthreads();                 // prev iter's fragment reads done
        #pragma unroll
        for (int j = 0; j < 4; j++) {
            gld16(ag[j] + k0, asw + j * 512);
            gld16(bg[j] + k0, bsw + j * 512);
        }
        __syncthreads();                 // vmcnt drain + barrier
        #pragma unroll
        for (int ks = 0; ks < 2; ks++) {
            bf16x8 af[4], bfr[4];
            #pragma unroll
            for (int i = 0; i < 4; i++) {
                af[i]  = *(const bf16x8*)(As + ((wr * 4 + i) * 2 + ks) * 512 + lane * 8);
                bfr[i] = *(const bf16x8*)(Bs + ((wn * 4 + i) * 2 + ks) * 512 + lane * 8);
            }
            #pragma unroll
            for (int mi = 0; mi < 4; mi++)
                #pragma unroll
                for (int ni = 0; ni < 4; ni++)
                    acc[mi][ni] = __builtin_amdgcn_mfma_f32_16x16x32_bf16(
                        af[mi], bfr[ni], acc[mi][ni], 0, 0, 0);
        }
    }
    // epilogue
    #pragma unroll
    for (int ni = 0; ni < 4; ni++) {
        const int col = n0 + wn * 64 + ni * 16 + l16;
        const float bv = bias[col];
        #pragma unroll
        for (int mi = 0; mi < 4; mi++) {
            #pragma unroll
            for (int r = 0; r < 4; r++) {
                const int row = m0 + wr * 64 + mi * 16 + quad * 4 + r;
                const size_t off = (size_t)row * ldc + col;
                float v = acc[mi][ni][r] + bv;
                if (MODE == 2) v = 0.5f * v * (1.0f + erff(v * 0.70710678118654752f));
                if (MODE == 1)
                    v += res_f32 ? ((const float*)res)[off]
                                 : (float)((const __bf16*)res)[off];
                if (OUTF) ((float*)C)[off] = v;
                else      ((__bf16*)C)[off] = (__bf16)v;
            }
        }
    }
}

// ---------------- fused QK^T * scale + rpb bias + softmax -> P -------------
// One block: 64 q-rows x full 256 k for one (window,head).  4 waves, each
// wave owns 16 q-rows (wave*16 + quad*4 + r), 16 col-blocks of 16.
__global__ __launch_bounds__(256) void qk_softmax(
    const __bf16* __restrict__ qkvb, const float* __restrict__ rpb,
    __bf16* __restrict__ Sc, int bh_base)
{
    __shared__ __align__(16) __bf16 Qs[64 * 72];
    __shared__ __align__(16) __bf16 Ks[256 * 72];
    __shared__ float rpbs[320];
    const int bhl = blockIdx.y;
    const int bh  = bh_base + bhl;
    const int bw = bh >> 3, head = bh & 7;
    const int m0 = blockIdx.x * 64;
    const int tid = threadIdx.x;
    const __bf16* qb = qkvb + (size_t)bw * WIN * 1536 + head * HD;

    {   // stage Q (64x64) and K (256x64), rows of 64 elems = 8 x bf16x8
        const int row = tid >> 3, l8 = (tid & 7) * 8;
        #pragma unroll
        for (int p = 0; p < 2; p++) {
            const int r = p * 32 + row;
            *(bf16x8*)(Qs + r * 72 + l8) =
                *(const bf16x8*)(qb + (size_t)(m0 + r) * 1536 + l8);
        }
        #pragma unroll
        for (int p = 0; p < 8; p++) {
            const int r = p * 32 + row;
            *(bf16x8*)(Ks + r * 72 + l8) =
                *(const bf16x8*)(qb + 512 + (size_t)r * 1536 + l8);
        }
        // rpb slice: bias(i,j) = rpb[i-j+255]; i-j+255-m0 in [0,318]
        rpbs[tid] = rpb[(size_t)(m0 + tid) * HEADS + head];
        if (tid < 63) rpbs[256 + tid] = rpb[(size_t)(m0 + 256 + tid) * HEADS + head];
    }
    __syncthreads();

    const int wave = tid >> 6, lane = tid & 63;
    const int quad = lane >> 4, l16 = lane & 15;
    bf16x8 af[2];
    #pragma unroll
    for (int ks = 0; ks < 2; ks++)
        af[ks] = *(const bf16x8*)(Qs + (wave * 16 + l16) * 72 + ks * 32 + quad * 8);

    f32x4 acc[16];
    #pragma unroll
    for (int nb = 0; nb < 16; nb++) acc[nb] = (f32x4){0.f, 0.f, 0.f, 0.f};
    #pragma unroll
    for (int nb = 0; nb < 16; nb++) {
        #pragma unroll
        for (int ks = 0; ks < 2; ks++) {
            bf16x8 bf = *(const bf16x8*)(Ks + (nb * 16 + l16) * 72 + ks * 32 + quad * 8);
            acc[nb] = __builtin_amdgcn_mfma_f32_16x16x32_bf16(af[ks], bf, acc[nb], 0, 0, 0);
        }
    }
    // scale + bias:  row li = wave*16+quad*4+r, col j = nb*16+l16
    #pragma unroll
    for (int nb = 0; nb < 16; nb++)
        #pragma unroll
        for (int r = 0; r < 4; r++) {
            const int li = wave * 16 + quad * 4 + r;
            acc[nb][r] = acc[nb][r] * 0.125f + rpbs[li - nb * 16 - l16 + 255];
        }
    // softmax per row r: reduce over nb (in-lane) then l16 (shfl within quad)
    __bf16* Sb = Sc + (size_t)bhl * (WIN * WIN);
    #pragma unroll
    for (int r = 0; r < 4; r++) {
        float m = -1e30f;
        #pragma unroll
        for (int nb = 0; nb < 16; nb++) m = fmaxf(m, acc[nb][r]);
        #pragma unroll
        for (int msk = 1; msk < 16; msk <<= 1) m = fmaxf(m, __shfl_xor(m, msk));
        float s = 0.f;
        #pragma unroll
        for (int nb = 0; nb < 16; nb++) { acc[nb][r] = __expf(acc[nb][r] - m); s += acc[nb][r]; }
        #pragma unroll
        for (int msk = 1; msk < 16; msk <<= 1) s += __shfl_xor(s, msk);
        const float inv = 1.0f / s;
        const int i = m0 + wave * 16 + quad * 4 + r;
        #pragma unroll
        for (int nb = 0; nb < 16; nb++)
            Sb[(size_t)i * WIN + nb * 16 + l16] = (__bf16)(acc[nb][r] * inv);
    }
}

// ---------------- 64x64 MFMA tile helper (pv) ------------------------------
__device__ __forceinline__ void mfma_tile64(
    const __bf16* __restrict__ A, int lda, int m0,
    const __bf16* __restrict__ Bt, int ldb, int n0,
    int K, f32x4* acc, __bf16* As, __bf16* Bs)
{
    const int tid  = threadIdx.x;
    const int wave = tid >> 6;
    const int lane = tid & 63;
    const int quad = lane >> 4;
    const int l16  = lane & 15;
    const int lrow = tid >> 2;          // 0..63
    const int lcol = (tid & 3) << 3;    // 0,8,16,24
    const __bf16* ap = A  + (size_t)(m0 + lrow) * lda + lcol;
    const __bf16* bp = Bt + (size_t)(n0 + lrow) * ldb + lcol;
    for (int k0 = 0; k0 < K; k0 += 32) {
        bf16x8 av = *(const bf16x8*)(ap + k0);
        bf16x8 bv = *(const bf16x8*)(bp + k0);
        __syncthreads();
        *(bf16x8*)(As + lrow * LDP + lcol) = av;
        *(bf16x8*)(Bs + lrow * LDP + lcol) = bv;
        __syncthreads();
        bf16x8 af = *(const bf16x8*)(As + (wave * 16 + l16) * LDP + (quad << 3));
        #pragma unroll
        for (int nb = 0; nb < 4; nb++) {
            bf16x8 bf = *(const bf16x8*)(Bs + (nb * 16 + l16) * LDP + (quad << 3));
            acc[nb] = __builtin_amdgcn_mfma_f32_16x16x32_bf16(af, bf, acc[nb], 0, 0, 0);
        }
    }
}

// ---------------- V^T per (window,head): Vt[d][j] = V[j][d] ----------------
__global__ __launch_bounds__(256) void vtrans(
    const __bf16* __restrict__ qkvb, __bf16* __restrict__ Vt, int bh_base)
{
    __shared__ __align__(16) __bf16 s[WIN * 72];
    const int bh = bh_base + blockIdx.x;
    const int bw = bh >> 3, head = bh & 7;
    const int tid = threadIdx.x;
    const __bf16* V = qkvb + (size_t)bw * WIN * 1536 + 1024 + head * HD;
    #pragma unroll
    for (int it = 0; it < 8; it++) {
        int idx = it * 256 + tid;
        int j = idx >> 3;
        int d0 = (idx & 7) * 8;
        *(bf16x8*)(s + j * 72 + d0) = *(const bf16x8*)(V + (size_t)j * 1536 + d0);
    }
    __syncthreads();
    __bf16* out = Vt + (size_t)blockIdx.x * (HD * WIN);
    #pragma unroll
    for (int it = 0; it < 8; it++) {
        int idx = it * 256 + tid;
        int d  = idx >> 5;
        int j0 = (idx & 31) * 8;
        bf16x8 v;
        #pragma unroll
        for (int j = 0; j < 8; j++) v[j] = s[(j0 + j) * 72 + d];
        *(bf16x8*)(out + (size_t)d * WIN + j0) = v;
    }
}

// ---------------- P@V -> attn_out ------------------------------------------
__global__ __launch_bounds__(256) void pv_gemm(
    const __bf16* __restrict__ Sc, const __bf16* __restrict__ Vt,
    __bf16* __restrict__ attnO, int bh_base)
{
    __shared__ __align__(16) __bf16 As[64 * LDP];
    __shared__ __align__(16) __bf16 Bs[64 * LDP];
    const int bhl = blockIdx.y;
    const int bh = bh_base + bhl;
    const int bw = bh >> 3, head = bh & 7;
    const int m0 = blockIdx.x * 64;
    const __bf16* P   = Sc + (size_t)bhl * (WIN * WIN);
    const __bf16* Vtb = Vt + (size_t)bhl * (HD * WIN);
    f32x4 acc[4] = {};
    mfma_tile64(P, WIN, m0, Vtb, WIN, 0, WIN, acc, As, Bs);
    const int lane = threadIdx.x & 63, wave = threadIdx.x >> 6;
    const int quad = lane >> 4, l16 = lane & 15;
    #pragma unroll
    for (int nb = 0; nb < 4; nb++) {
        const int d = nb * 16 + l16;
        #pragma unroll
        for (int r = 0; r < 4; r++) {
            const int i = m0 + wave * 16 + quad * 4 + r;
            attnO[(size_t)(bw * WIN + i) * DIMC + head * HD + d] = (__bf16)acc[nb][r];
        }
    }
}

// ---------------- LayerNorm: one wave per token ----------------------------
__global__ __launch_bounds__(256) void ln_kernel(
    const void* X, int xf,
    const float* __restrict__ g, const float* __restrict__ b,
    __bf16* O)
{
    const int tok  = blockIdx.x * 4 + (threadIdx.x >> 6);
    const int lane = threadIdx.x & 63;
    const size_t base = (size_t)tok * DIMC + lane * 8;
    float v[8];
    if (xf) {
        const float* xp = (const float*)X + base;
        f32x4 a = *(const f32x4*)xp;
        f32x4 c = *(const f32x4*)(xp + 4);
        #pragma unroll
        for (int j = 0; j < 4; j++) { v[j] = a[j]; v[4 + j] = c[j]; }
    } else {
        bf16x8 xv = *(const bf16x8*)((const __bf16*)X + base);
        #pragma unroll
        for (int j = 0; j < 8; j++) v[j] = (float)xv[j];
    }
    float s = 0.f, s2 = 0.f;
    #pragma unroll
    for (int j = 0; j < 8; j++) { s += v[j]; s2 += v[j] * v[j]; }
    #pragma unroll
    for (int off = 32; off; off >>= 1) { s += __shfl_xor(s, off); s2 += __shfl_xor(s2, off); }
    const float mean = s * (1.0f / DIMC);
    const float var  = s2 * (1.0f / DIMC) - mean * mean;
    const float rstd = rsqrtf(var + 1e-5f);
    f32x4 ga = *(const f32x4*)(g + lane * 8);
    f32x4 gc = *(const f32x4*)(g + lane * 8 + 4);
    f32x4 ba = *(const f32x4*)(b + lane * 8);
    f32x4 bc = *(const f32x4*)(b + lane * 8 + 4);
    bf16x8 ov;
    #pragma unroll
    for (int j = 0; j < 4; j++) {
        ov[j]     = (__bf16)((v[j]     - mean) * rstd * ga[j] + ba[j]);
        ov[4 + j] = (__bf16)((v[4 + j] - mean) * rstd * gc[j] + bc[j]);
    }
    *(bf16x8*)(O + base) = ov;
}

// ---------------- weight transpose+cast: fp32 KxN -> bf16 NxK --------------
__global__ __launch_bounds__(256) void wtrans(
    const float* __restrict__ W, __bf16* __restrict__ Wt, int K, int N)
{
    __shared__ __align__(16) __bf16 s[64 * 72];
    const int kb = blockIdx.y * 64, nb = blockIdx.x * 64;
    const int tid = threadIdx.x;
    #pragma unroll
    for (int it = 0; it < 2; it++) {
        int idx = it * 256 + tid;
        int lk = idx >> 3;
        int ln = (idx & 7) * 8;
        const float* wp = W + (size_t)(kb + lk) * N + nb + ln;
        f32x4 a = *(const f32x4*)wp;
        f32x4 c = *(const f32x4*)(wp + 4);
        bf16x8 v;
        #pragma unroll
        for (int j = 0; j < 4; j++) { v[j] = (__bf16)a[j]; v[4 + j] = (__bf16)c[j]; }
        *(bf16x8*)(s + lk * 72 + ln) = v;
    }
    __syncthreads();
    #pragma unroll
    for (int it = 0; it < 2; it++) {
        int idx = it * 256 + tid;
        int ln  = idx >> 3;
        int lkv = (idx & 7) * 8;
        bf16x8 v;
        #pragma unroll
        for (int j = 0; j < 8; j++) v[j] = s[(lkv + j) * 72 + ln];
        *(bf16x8*)(Wt + (size_t)(nb + ln) * K + kb + lkv) = v;
    }
}

// ---------------------------------------------------------------------------
extern "C" void kernel_launch(void* const* d_in, const int* in_sizes, int n_in,
                              void* d_out, int out_size, void* d_ws, size_t ws_size,
                              hipStream_t stream)
{
    const float* x      = (const float*)d_in[0];
    const float* n1g    = (const float*)d_in[1];
    const float* n1b    = (const float*)d_in[2];
    const float* qkv_w  = (const float*)d_in[3];
    const float* qkv_b  = (const float*)d_in[4];
    const float* rpb    = (const float*)d_in[5];
    const float* proj_w = (const float*)d_in[6];
    const float* proj_b = (const float*)d_in[7];
    const float* n2g    = (const float*)d_in[8];
    const float* n2b    = (const float*)d_in[9];
    const float* fc1_w  = (const float*)d_in[10];
    const float* fc1_b  = (const float*)d_in[11];
    const float* fc2_w  = (const float*)d_in[12];
    const float* fc2_b  = (const float*)d_in[13];
    float* out = (float*)d_out;

    // workspace layout (bytes), 216 MB peak; slots reused sequentially
    char* ws = (char*)d_ws;
    __bf16* qkvb  = (__bf16*)(ws + 0);
    __bf16* hid   = (__bf16*)(ws + 0);
    __bf16* h     = (__bf16*)(ws + 134217728);   // also Sc slot, also y/x2
    __bf16* Sc    = h;
    __bf16* y     = h;
    __bf16* attnO = (__bf16*)(ws + 167772160);
    __bf16* Vt    = (__bf16*)(ws + 201326592);
    __bf16* wq_t  = (__bf16*)(ws + 209715200);   // 1536x512
    __bf16* wp_t  = (__bf16*)(ws + 211288064);   // 512x512
    __bf16* w1_t  = (__bf16*)(ws + 211812352);   // 2048x512
    __bf16* w2_t  = (__bf16*)(ws + 213909504);   // 512x2048

    // 1) weight transposes (tiny)
    wtrans<<<dim3(1536 / 64, 512 / 64),  256, 0, stream>>>(qkv_w, wq_t, 512, 1536);
    wtrans<<<dim3(512 / 64,  512 / 64),  256, 0, stream>>>(proj_w, wp_t, 512, 512);
    wtrans<<<dim3(2048 / 64, 512 / 64),  256, 0, stream>>>(fc1_w, w1_t, 512, 2048);
    wtrans<<<dim3(512 / 64,  2048 / 64), 256, 0, stream>>>(fc2_w, w2_t, 2048, 512);

    // 2) LN1: h = LN(x)
    ln_kernel<<<NTOK / 4, 256, 0, stream>>>(x, 1, n1g, n1b, h);

    // 3) qkv = h @ qkv_w + qkv_b   (M=32768, N=1536, K=512); nM=256 nN=12
    gemm128<0, 0><<<3072, 256, 0, stream>>>(
        h, DIMC, wq_t, DIMC, qkv_b, nullptr, 0, qkvb, 1536, DIMC, 256, 12);

    // 4) attention in 4 chunks of 256 (window,head) pairs
    for (int c = 0; c < 4; c++) {
        const int bh0 = c * 256;
        vtrans<<<256, 256, 0, stream>>>(qkvb, Vt, bh0);
        qk_softmax<<<dim3(4, 256), 256, 0, stream>>>(qkvb, rpb, Sc, bh0);
        pv_gemm<<<dim3(4, 256), 256, 0, stream>>>(Sc, Vt, attnO, bh0);
    }

    // 5) y = x + attnO @ proj_w + proj_b   (N=512, K=512); nM=256 nN=4
    gemm128<1, 0><<<1024, 256, 0, stream>>>(
        attnO, DIMC, wp_t, DIMC, proj_b, x, 1, y, DIMC, DIMC, 256, 4);

    // 6) LN2 in place: x2 = LN(y)
    ln_kernel<<<NTOK / 4, 256, 0, stream>>>(y, 0, n2g, n2b, y);

    // 7) hid = gelu(x2 @ fc1_w + fc1_b)   (N=2048, K=512); nM=256 nN=16
    gemm128<2, 0><<<4096, 256, 0, stream>>>(
        y, DIMC, w1_t, DIMC, fc1_b, nullptr, 0, hid, HIDC, DIMC, 256, 16);

    // 8) out(fp32) = x2 + hid @ fc2_w + fc2_b  (N=512, K=2048); nM=256 nN=4
    gemm128<1, 1><<<1024, 256, 0, stream>>>(
        hid, HIDC, w2_t, HIDC, fc2_b, y, 0, out, DIMC, HIDC, 256, 4);
}